// Round 21
// baseline (99.279 us; speedup 1.0000x reference)
//
#include <hip/hip_runtime.h>
#include <math.h>

#define AS3 __attribute__((address_space(3)))
#define AS1 __attribute__((address_space(1)))

typedef unsigned short u16;
typedef unsigned int u32;
typedef __bf16 bf16_t;
typedef bf16_t bf16x8 __attribute__((ext_vector_type(8)));
typedef float f32x4 __attribute__((ext_vector_type(4)));
typedef float f32x16 __attribute__((ext_vector_type(16)));
typedef unsigned short u16x4 __attribute__((ext_vector_type(4)));
typedef unsigned short u16x8 __attribute__((ext_vector_type(8)));
typedef unsigned int u32x2 __attribute__((ext_vector_type(2)));
typedef unsigned int u32x4 __attribute__((ext_vector_type(4)));

#define NH 16
#define DK 64
#define DC 256
#define DM 1024
#define BB 2
#define SS 2048
#define TT (BB*SS)

__device__ __forceinline__ u16 f2bf(float f) {
    unsigned u = __builtin_bit_cast(unsigned, f);
    unsigned r = (u + 0x7FFFu + ((u >> 16) & 1u)) >> 16;
    return (u16)r;
}

__device__ __forceinline__ float bf2f(u16 h) {
    u32 u = ((u32)h) << 16;
    return __builtin_bit_cast(float, u);
}

__device__ __forceinline__ u32 cvtpk_bf16(float a, float b) {
    u32 d;
    asm("v_cvt_pk_bf16_f32 %0, %1, %2" : "=v"(d) : "v"(a), "v"(b));
    return d;
}

__device__ __forceinline__ bf16x8 lds_frag(const char* p) {
    return __builtin_bit_cast(bf16x8, *reinterpret_cast<const u16x8*>(p));
}

// ---------------- prep: 6 weight transposes (fp32 [K][N] -> bf16 [N][K]) ----------------
__global__ __launch_bounds__(256) void prep(const float* w0, const float* w1, const float* w2,
                                            const float* w3, const float* w4, const float* w5,
                                            u16* d0, u16* d1, u16* d2, u16* d3, u16* d4, u16* d5) {
    __shared__ float t[32][33];
    const int z = blockIdx.z;
    const float* src; u16* dst; int R, C, opitch;
    switch (z) {
        case 0:  src = w0; dst = d0; R = 1024; C = 256;  opitch = 1024; break;
        case 1:  src = w1; dst = d1; R = 1024; C = 256;  opitch = 1024; break;
        case 2:  src = w2; dst = d2; R = 256;  C = 1024; opitch = 256;  break;
        case 3:  src = w3; dst = d3; R = 256;  C = 1024; opitch = 256;  break;
        case 4:  src = w4; dst = d4; R = 256;  C = 1024; opitch = 256;  break;
        default: src = w5; dst = d5; R = 1024; C = 1024; opitch = 1024; break;
    }
    int c0 = blockIdx.x * 32, r0 = blockIdx.y * 32;
    if (c0 >= C || r0 >= R) return;
    int tx = threadIdx.x & 31, ty = threadIdx.x >> 5;
    #pragma unroll
    for (int p = 0; p < 4; ++p)
        t[ty + 8 * p][tx] = src[(r0 + ty + 8 * p) * C + c0 + tx];
    __syncthreads();
    #pragma unroll
    for (int p = 0; p < 4; ++p)
        dst[(c0 + ty + 8 * p) * opitch + r0 + tx] = f2bf(t[tx][ty + 8 * p]);
}

// ---------------- gemm_dqkv: c_qkv[4096,512] = x(f32) @ Wdqkv_t^T, BK=64 ----------------
// grid (64, 8): blockIdx.x = bm-panel -> all 8 bn-tiles share the A-panel on one XCD L2
__global__ __launch_bounds__(256) void gemm_dqkv(const float* __restrict__ X,
                                                 const u16* __restrict__ Bt,
                                                 u16* __restrict__ Cc) {
    __shared__ u16 As[2][64 * 32];
    __shared__ u16 Bs[2][64 * 32];
    const int tid = threadIdx.x;
    const int lane = tid & 63;
    const int w = tid >> 6;
    const int wr = w >> 1, wc = w & 1;
    const int bm = blockIdx.x * 64, bn = blockIdx.y * 64;
    const int l15 = lane & 15, l4 = lane >> 4;
    const int arow = tid >> 2, akc = (tid & 3) * 8;

    f32x4 acc[2][2] = {};

    for (int k0 = 0; k0 < 1024; k0 += 64) {
        #pragma unroll
        for (int h = 0; h < 2; ++h) {
            const float* xp = X + (size_t)(bm + arow) * 1024 + k0 + h * 32 + akc;
            float4 v0 = *reinterpret_cast<const float4*>(xp);
            float4 v1 = *reinterpret_cast<const float4*>(xp + 4);
            u32x4 o;
            o.x = cvtpk_bf16(v0.x, v0.y);
            o.y = cvtpk_bf16(v0.z, v0.w);
            o.z = cvtpk_bf16(v1.x, v1.y);
            o.w = cvtpk_bf16(v1.z, v1.w);
            *reinterpret_cast<u32x4*>(&As[h][arow * 32 + akc]) = o;
        }
        #pragma unroll
        for (int h = 0; h < 2; ++h) {
            __builtin_amdgcn_global_load_lds(
                (const AS1 void*)(Bt + (size_t)(bn + arow) * 1024 + k0 + h * 32 + akc),
                (AS3 void*)((AS3 char*)(AS3 void*)&Bs[h][0] + w * 1024), 16, 0, 0);
        }
        __syncthreads();
        #pragma unroll
        for (int h = 0; h < 2; ++h) {
            bf16x8 a[2], b[2];
            #pragma unroll
            for (int m = 0; m < 2; ++m)
                a[m] = __builtin_bit_cast(bf16x8,
                    *reinterpret_cast<const u16x8*>(&As[h][(wr * 32 + m * 16 + l15) * 32 + l4 * 8]));
            #pragma unroll
            for (int n = 0; n < 2; ++n)
                b[n] = __builtin_bit_cast(bf16x8,
                    *reinterpret_cast<const u16x8*>(&Bs[h][(wc * 32 + n * 16 + l15) * 32 + l4 * 8]));
            #pragma unroll
            for (int m = 0; m < 2; ++m)
                #pragma unroll
                for (int n = 0; n < 2; ++n)
                    acc[m][n] = __builtin_amdgcn_mfma_f32_16x16x32_bf16(a[m], b[n], acc[m][n], 0, 0, 0);
        }
        __syncthreads();
    }
    #pragma unroll
    for (int m = 0; m < 2; ++m) {
        int row = bm + wr * 32 + m * 16 + l4 * 4;
        #pragma unroll
        for (int j = 0; j < 4; ++j)
            #pragma unroll
            for (int n = 0; n < 2; ++n) {
                int col = bn + wc * 32 + n * 16 + l15;
                Cc[(size_t)(row + j) * 512 + col] = f2bf(acc[m][n][j]);
            }
    }
}

// ---------------- gemm_out: out[4096,1024](f32) = attno @ Wo_t^T, BK=64 ----------------
// grid (64, 8): blockIdx.x = bm-panel (same-XCD A-panel sharing)
__global__ __launch_bounds__(256) void gemm_out(const u16* __restrict__ A,
                                                const u16* __restrict__ Bt,
                                                float* __restrict__ C) {
    __shared__ u16 As[2][64 * 32];
    __shared__ u16 Bs[2][128 * 32];
    const int tid = threadIdx.x;
    const int lane = tid & 63;
    const int w = tid >> 6;
    const int wr = w >> 1, wc = w & 1;
    const int bm = blockIdx.x * 64, bn = blockIdx.y * 128;
    const int l15 = lane & 15, l4 = lane >> 4;

    f32x4 acc[2][4] = {};

    for (int k0 = 0; k0 < 1024; k0 += 64) {
        #pragma unroll
        for (int h = 0; h < 2; ++h) {
            {
                int db = tid * 16;
                int row = db >> 6;
                int kc = (db & 63) >> 1;
                __builtin_amdgcn_global_load_lds(
                    (const AS1 void*)(A + (size_t)(bm + row) * 1024 + k0 + h * 32 + kc),
                    (AS3 void*)((AS3 char*)(AS3 void*)&As[h][0] + w * 1024), 16, 0, 0);
            }
            #pragma unroll
            for (int i = 0; i < 2; ++i) {
                int db = i * 4096 + tid * 16;
                int row = db >> 6;
                int kc = (db & 63) >> 1;
                __builtin_amdgcn_global_load_lds(
                    (const AS1 void*)(Bt + (size_t)(bn + row) * 1024 + k0 + h * 32 + kc),
                    (AS3 void*)((AS3 char*)(AS3 void*)&Bs[h][0] + i * 4096 + w * 1024), 16, 0, 0);
            }
        }
        __syncthreads();
        #pragma unroll
        for (int h = 0; h < 2; ++h) {
            bf16x8 a[2], b[4];
            #pragma unroll
            for (int m = 0; m < 2; ++m)
                a[m] = __builtin_bit_cast(bf16x8,
                    *reinterpret_cast<const u16x8*>(&As[h][(wr * 32 + m * 16 + l15) * 32 + l4 * 8]));
            #pragma unroll
            for (int n = 0; n < 4; ++n)
                b[n] = __builtin_bit_cast(bf16x8,
                    *reinterpret_cast<const u16x8*>(&Bs[h][(wc * 64 + n * 16 + l15) * 32 + l4 * 8]));
            #pragma unroll
            for (int m = 0; m < 2; ++m)
                #pragma unroll
                for (int n = 0; n < 4; ++n)
                    acc[m][n] = __builtin_amdgcn_mfma_f32_16x16x32_bf16(a[m], b[n], acc[m][n], 0, 0, 0);
        }
        __syncthreads();
    }
    #pragma unroll
    for (int m = 0; m < 2; ++m) {
        int row = bm + wr * 32 + m * 16 + l4 * 4;
        #pragma unroll
        for (int j = 0; j < 4; ++j)
            #pragma unroll
            for (int n = 0; n < 4; ++n) {
                int col = bn + wc * 64 + n * 16 + l15;
                C[(size_t)(row + j) * 1024 + col] = acc[m][n][j];
            }
    }
}

// ---------------- MFMA GEMM body (128x128, BK=32) for the fused QKV projection ----------------
template <int OUT_MODE>
__device__ __forceinline__ void gemm_body128(const u16* __restrict__ A, int lda,
                                             const u16* __restrict__ Bt, int ldb,
                                             void* __restrict__ C, int ldc, int K,
                                             int bm, int bn, u16* As, u16* Bs) {
    const int tid = threadIdx.x;
    const int lane = tid & 63;
    const int w = tid >> 6;
    const int wr = w >> 1, wc = w & 1;
    const int l15 = lane & 15, l4 = lane >> 4;

    f32x4 acc[4][4] = {};

    for (int k0 = 0; k0 < K; k0 += 32) {
        #pragma unroll
        for (int i = 0; i < 2; ++i) {
            int db = i * 4096 + tid * 16;
            int row = db >> 6;
            int kc = (db & 63) >> 1;
            __builtin_amdgcn_global_load_lds(
                (const AS1 void*)(A + (size_t)(bm + row) * lda + k0 + kc),
                (AS3 void*)((AS3 char*)(AS3 void*)As + i * 4096 + w * 1024), 16, 0, 0);
            __builtin_amdgcn_global_load_lds(
                (const AS1 void*)(Bt + (size_t)(bn + row) * ldb + k0 + kc),
                (AS3 void*)((AS3 char*)(AS3 void*)Bs + i * 4096 + w * 1024), 16, 0, 0);
        }
        __syncthreads();
        bf16x8 a[4], b[4];
        #pragma unroll
        for (int m = 0; m < 4; ++m)
            a[m] = __builtin_bit_cast(bf16x8,
                *reinterpret_cast<const u16x8*>(&As[(wr * 64 + m * 16 + l15) * 32 + l4 * 8]));
        #pragma unroll
        for (int n = 0; n < 4; ++n)
            b[n] = __builtin_bit_cast(bf16x8,
                *reinterpret_cast<const u16x8*>(&Bs[(wc * 64 + n * 16 + l15) * 32 + l4 * 8]));
        #pragma unroll
        for (int m = 0; m < 4; ++m)
            #pragma unroll
            for (int n = 0; n < 4; ++n)
                acc[m][n] = __builtin_amdgcn_mfma_f32_16x16x32_bf16(a[m], b[n], acc[m][n], 0, 0, 0);
        __syncthreads();
    }
    if (OUT_MODE == 2) {
        #pragma unroll
        for (int m = 0; m < 4; ++m) {
            int row = bm + wr * 64 + m * 16 + l4 * 4;   // = b*2048 + s, s%4==0
            int vrow_base = (row >> 11) << 10;
            int scol = row & 2047;
            #pragma unroll
            for (int n = 0; n < 4; ++n) {
                int col = bn + wc * 64 + n * 16 + l15;   // v-dim
                u16x4 ov;
                ov[0] = f2bf(acc[m][n][0]); ov[1] = f2bf(acc[m][n][1]);
                ov[2] = f2bf(acc[m][n][2]); ov[3] = f2bf(acc[m][n][3]);
                *reinterpret_cast<u16x4*>((u16*)C + (size_t)(vrow_base + col) * 2048 + scol) = ov;
            }
        }
    } else {
        #pragma unroll
        for (int m = 0; m < 4; ++m) {
            int row = bm + wr * 64 + m * 16 + l4 * 4;
            #pragma unroll
            for (int j = 0; j < 4; ++j)
                #pragma unroll
                for (int n = 0; n < 4; ++n) {
                    int col = bn + wc * 64 + n * 16 + l15;
                    ((u16*)C)[(size_t)(row + j) * ldc + col] = f2bf(acc[m][n][j]);
                }
        }
    }
}

// fused Q + K + V up-projection, K=256. grid (32, 24): blockIdx.x = bm-panel.
__global__ __launch_bounds__(256) void gemm_qkv(const u16* __restrict__ c_qkv,
                                                const u16* __restrict__ Wuq_t,
                                                const u16* __restrict__ Wukv_t,
                                                u16* __restrict__ Qb, u16* __restrict__ Kb,
                                                u16* __restrict__ Vt) {
    __shared__ u16 As[128 * 32];
    __shared__ u16 Bs[128 * 32];
    const int by = blockIdx.y;
    const int bm = blockIdx.x * 128;
    if (by < 8) {
        gemm_body128<1>(c_qkv, 512, Wuq_t, 256, Qb, 1024, 256,
                        bm, by * 128, As, Bs);
    } else if (by < 16) {
        gemm_body128<1>(c_qkv + 256, 512, Wukv_t, 256, Kb, 1024, 256,
                        bm, (by - 8) * 128, As, Bs);
    } else {
        gemm_body128<2>(c_qkv + 256, 512, Wukv_t + 1024 * 256, 256, Vt, 0, 256,
                        bm, (by - 16) * 128, As, Bs);
    }
}

// ---------------- MFMA causal flash attention v14: 128 q-rows / 8 waves ----------------
// Block = (bq 128 q-rows, bh), 512 threads. Wave w: pair = w&1 (tile parity),
// qs = w>>2^..  qs = w>>1 (q-slice). Per round stage 2 tiles (32 KB) feeding all
// 128 rows -> rounds/CU and staged bytes halve vs the 64-row version.
// Max-free softmax (R19); cross-parity merge: parity-1 publishes bf16 partials,
// parity-0 merges in-register and stores O directly (R6-style epilogue).
__global__ __launch_bounds__(512, 4) void attn_mfma8(const u16* __restrict__ Qb,
                                                     const u16* __restrict__ Kb,
                                                     const u16* __restrict__ VtG,
                                                     u16* __restrict__ O) {
    __shared__ char lds[32768];   // 2 slots x (8KB K + 8KB V); epilogue aliases 19 KB
    const int bid = blockIdx.x;
    const int g = bid >> 8, u = (bid >> 5) & 7;
    const int bq = g ? u : (15 - u);     // per-CU pair {15-u, u}: 17 rounds each CU
    const int bh = bid & 31;
    const int b = bh >> 4, head = bh & 15;
    const int tid = threadIdx.x;
    const int w = tid >> 6;              // 0..7
    const int lane = tid & 63;
    const int l31 = lane & 31, hi = lane >> 5;
    const int r7 = l31 & 7;
    const int pair = w & 1;              // tile parity
    const int qs = w >> 1;               // q-slice 0..3
    const int q0 = bq * 128;
    const int qbase = q0 + qs * 32;      // wave's first q row
    const int qg = qbase + l31;
    const int qtop = qbase + 31;
    const int rounds = bq + 1;           // tiles 0..2bq+1, 2 per round
    const float c2 = 0.125f * 1.44269504088896340736f;  // scale * log2(e)

    // Q fragments (B-operand): Q[q][16kc + 8hi + 0..7]
    bf16x8 qf[4];
    {
        const u16* qp = Qb + (size_t)(b * SS + qg) * 1024 + head * 64 + hi * 8;
        #pragma unroll
        for (int kc = 0; kc < 4; ++kc)
            qf[kc] = __builtin_bit_cast(bf16x8, *reinterpret_cast<const u16x8*>(qp + kc * 16));
    }

    f32x16 acc0 = {}, acc1 = {};   // O^T partial: d rows (0..31 / 32..63), col = q
    float lrow = 0.f;

    const int srow = tid >> 3;                  // 0..63
    const int ssc = (tid & 7) ^ (srow & 7);     // inverse-swizzled 16B chunk

    for (int r = 0; r < rounds; ++r) {
        // stage both parity slots: 512 threads x 16B per buffer
        #pragma unroll
        for (int p_ = 0; p_ < 2; ++p_) {
            const int k0_ = (2 * r + p_) * 64;
            char* base_ = lds + p_ * 16384;
            __builtin_amdgcn_global_load_lds(
                (const AS1 void*)(Kb + (size_t)(b * SS + k0_ + srow) * 1024 + head * 64 + ssc * 8),
                (AS3 void*)((AS3 char*)(AS3 void*)base_ + w * 1024), 16, 0, 0);
            __builtin_amdgcn_global_load_lds(
                (const AS1 void*)(VtG + (size_t)(bh * 64 + srow) * 2048 + k0_ + ssc * 8),
                (AS3 void*)((AS3 char*)(AS3 void*)base_ + 8192 + w * 1024), 16, 0, 0);
        }
        __syncthreads();   // staging complete
        const int kt = 2 * r + pair;
        if (kt * 64 <= qtop) {   // skip tiles fully beyond this wave's causal range
            const char* Kb_ = lds + pair * 16384;
            const char* Vb_ = Kb_ + 8192;
            const int k0 = kt * 64;
            // S^T = K @ Q^T
            f32x16 s0 = {}, s1 = {};
            __builtin_amdgcn_s_setprio(1);
            #pragma unroll
            for (int kc = 0; kc < 4; ++kc) {
                bf16x8 kf0 = lds_frag(Kb_ + (l31) * 128 + ((2 * kc + hi) ^ r7) * 16);
                bf16x8 kf1 = lds_frag(Kb_ + (32 + l31) * 128 + ((2 * kc + hi) ^ r7) * 16);
                s0 = __builtin_amdgcn_mfma_f32_32x32x16_bf16(kf0, qf[kc], s0, 0, 0, 0);
                s1 = __builtin_amdgcn_mfma_f32_32x32x16_bf16(kf1, qf[kc], s1, 0, 0, 0);
            }
            __builtin_amdgcn_s_setprio(0);
            if (k0 + 63 > qbase) {   // tile overlaps the causal diagonal for this wave
                const int lim = qg - k0 - hi * 4;
                #pragma unroll
                for (int r2 = 0; r2 < 16; ++r2) {
                    const int ko = (r2 & 3) + 8 * (r2 >> 2);
                    s0[r2] = (ko > lim) ? -3.0e38f : s0[r2];
                    s1[r2] = (ko + 32 > lim) ? -3.0e38f : s1[r2];
                }
            }
            // max-free softmax: p = exp2(s * c2)
            #pragma unroll
            for (int r2 = 0; r2 < 16; ++r2) {
                s0[r2] = exp2f(s0[r2] * c2);
                s1[r2] = exp2f(s1[r2] * c2);
            }
            float c8[8];
            #pragma unroll
            for (int i = 0; i < 8; ++i)
                c8[i] = (s0[2 * i] + s0[2 * i + 1]) + (s1[2 * i] + s1[2 * i + 1]);
            float rsum = ((c8[0] + c8[1]) + (c8[2] + c8[3])) + ((c8[4] + c8[5]) + (c8[6] + c8[7]));
            rsum += __shfl_xor(rsum, 32);
            lrow += rsum;
            // pack P to bf16 pairs
            u32 cg0[4][2], cg1[4][2];
            #pragma unroll
            for (int gg = 0; gg < 4; ++gg) {
                #pragma unroll
                for (int w2 = 0; w2 < 2; ++w2) {
                    cg0[gg][w2] = cvtpk_bf16(s0[4 * gg + 2 * w2], s0[4 * gg + 2 * w2 + 1]);
                    cg1[gg][w2] = cvtpk_bf16(s1[4 * gg + 2 * w2], s1[4 * gg + 2 * w2 + 1]);
                }
            }
            // assemble P frags via shfl_xor(32): pa[ks] = P[q][16ks + 8hi + 0..7]
            bf16x8 pa[4];
            #pragma unroll
            for (int ks = 0; ks < 4; ++ks) {
                const int g0 = (2 * ks) & 3, g1 = g0 + 1;
                u32 a0, a1, b0, b1;
                if (ks < 2) { a0 = cg0[g0][0]; a1 = cg0[g0][1]; b0 = cg0[g1][0]; b1 = cg0[g1][1]; }
                else        { a0 = cg1[g0][0]; a1 = cg1[g0][1]; b0 = cg1[g1][0]; b1 = cg1[g1][1]; }
                u32 pa0 = (u32)__shfl_xor((int)a0, 32);
                u32 pa1 = (u32)__shfl_xor((int)a1, 32);
                u32 pb0 = (u32)__shfl_xor((int)b0, 32);
                u32 pb1 = (u32)__shfl_xor((int)b1, 32);
                u32x4 f;
                f.x = hi ? pb0 : a0;
                f.y = hi ? pb1 : a1;
                f.z = hi ? b0 : pa0;
                f.w = hi ? b1 : pa1;
                pa[ks] = __builtin_bit_cast(bf16x8, f);
            }
            // O^T += V^T @ P^T
            __builtin_amdgcn_s_setprio(1);
            #pragma unroll
            for (int ks = 0; ks < 4; ++ks) {
                bf16x8 vf0 = lds_frag(Vb_ + (l31) * 128 + ((2 * ks + hi) ^ r7) * 16);
                bf16x8 vf1 = lds_frag(Vb_ + (32 + l31) * 128 + ((2 * ks + hi) ^ r7) * 16);
                acc0 = __builtin_amdgcn_mfma_f32_32x32x16_bf16(vf0, pa[ks], acc0, 0, 0, 0);
                acc1 = __builtin_amdgcn_mfma_f32_32x32x16_bf16(vf1, pa[ks], acc1, 0, 0, 0);
            }
            __builtin_amdgcn_s_setprio(0);
        }
        __syncthreads();   // all reads done; safe to restage next round
    }

    // parity-1 publishes bf16 partials + l (aliases staging; all reads done)
    u16* partb = (u16*)lds;               // [4][32][72] u16 = 18432 B
    float* l1 = (float*)(lds + 18432);    // [4][32] f32 = 512 B
    if (pair == 1) {
        #pragma unroll
        for (int r2 = 0; r2 < 16; r2 += 2) {
            const int d0 = (r2 & 3) + 8 * (r2 >> 2) + 4 * hi;
            *reinterpret_cast<u32*>(&partb[(qs * 32 + l31) * 72 + d0]) =
                cvtpk_bf16(acc0[r2], acc0[r2 + 1]);
            *reinterpret_cast<u32*>(&partb[(qs * 32 + l31) * 72 + d0 + 32]) =
                cvtpk_bf16(acc1[r2], acc1[r2 + 1]);
        }
        if (hi == 0) l1[qs * 32 + l31] = lrow;
    }
    __syncthreads();
    // parity-0 merges in-register and stores O directly (R6-style epilogue)
    if (pair == 0) {
        const float inv = 1.0f / (lrow + l1[qs * 32 + l31]);
        u16* orow = O + (size_t)(b * SS + qbase + l31) * 1024 + head * 64 + 4 * hi;
        #pragma unroll
        for (int k = 0; k < 4; ++k) {
            u16x4 p0 = *reinterpret_cast<const u16x4*>(&partb[(qs * 32 + l31) * 72 + 8 * k + 4 * hi]);
            u16x4 p1 = *reinterpret_cast<const u16x4*>(&partb[(qs * 32 + l31) * 72 + 8 * k + 4 * hi + 32]);
            float m0 = (acc0[4 * k + 0] + bf2f(p0[0])) * inv;
            float m1 = (acc0[4 * k + 1] + bf2f(p0[1])) * inv;
            float m2 = (acc0[4 * k + 2] + bf2f(p0[2])) * inv;
            float m3 = (acc0[4 * k + 3] + bf2f(p0[3])) * inv;
            u32x2 o0;
            o0.x = cvtpk_bf16(m0, m1);
            o0.y = cvtpk_bf16(m2, m3);
            *reinterpret_cast<u32x2*>(orow + 8 * k) = o0;
            float n0 = (acc1[4 * k + 0] + bf2f(p1[0])) * inv;
            float n1 = (acc1[4 * k + 1] + bf2f(p1[1])) * inv;
            float n2 = (acc1[4 * k + 2] + bf2f(p1[2])) * inv;
            float n3 = (acc1[4 * k + 3] + bf2f(p1[3])) * inv;
            u32x2 o1;
            o1.x = cvtpk_bf16(n0, n1);
            o1.y = cvtpk_bf16(n2, n3);
            *reinterpret_cast<u32x2*>(orow + 32 + 8 * k) = o1;
        }
    }
}

// ---------------- launch ----------------

extern "C" void kernel_launch(void* const* d_in, const int* in_sizes, int n_in,
                              void* d_out, int out_size, void* d_ws, size_t ws_size,
                              hipStream_t stream) {
    const float* x     = (const float*)d_in[0];
    const float* W_dq  = (const float*)d_in[1];
    const float* W_uq  = (const float*)d_in[2];
    const float* W_dkv = (const float*)d_in[3];
    const float* W_uk  = (const float*)d_in[4];
    const float* W_uv  = (const float*)d_in[5];
    const float* W_o   = (const float*)d_in[6];
    float* out = (float*)d_out;

    char* ws = (char*)d_ws;
    u16* c_qkv   = (u16*)(ws + (8u << 20));             // 4 MB   [4096][512]
    u16* Qb      = (u16*)(ws + (12u << 20));            // 8 MB   [4096][1024]
    u16* Kb      = (u16*)(ws + (20u << 20));            // 8 MB   [4096][1024] (K only)
    u16* Vt      = (u16*)(ws + (36u << 20));            // 8 MB   [2048][2048]
    u16* attno   = (u16*)(ws + (44u << 20));            // 8 MB   [4096][1024]
    u16* Wdqkv_t = (u16*)(ws + (52u << 20));            // 1 MB   [512][1024]
    u16* Wuq_t   = (u16*)(ws + (53u << 20));            // 0.5 MB [1024][256]
    u16* Wukv_t  = (u16*)(ws + (53u << 20) + (512u << 10)); // 1 MB [2048][256]
    u16* Wo_t    = (u16*)(ws + (55u << 20));            // 2 MB   [1024][1024]

    dim3 blk(256);
    // 6 weight transposes
    prep<<<dim3(32, 32, 6), blk, 0, stream>>>(W_dq, W_dkv, W_uq, W_uk, W_uv, W_o,
        Wdqkv_t, Wdqkv_t + 256 * 1024, Wuq_t, Wukv_t, Wukv_t + 1024 * 256, Wo_t);
    // c_qkv = x(f32) @ [W_dq | W_dkv]   grid (64,8): A-panel-per-XCD
    gemm_dqkv<<<dim3(64, 8), blk, 0, stream>>>(x, Wdqkv_t, c_qkv);
    // Q | K | V(transposed) up-projection, K=256, grid (32,24): A-panel-per-XCD
    gemm_qkv<<<dim3(32, 24), blk, 0, stream>>>(c_qkv, Wuq_t, Wukv_t, Qb, Kb, Vt);
    // attention: 512 blocks x 512 threads, 128 q-rows/block, balanced per-CU map
    attn_mfma8<<<dim3(512), dim3(512), 0, stream>>>(Qb, Kb, Vt, attno);
    // out = attno @ W_o   grid (64,8): A-panel-per-XCD, fp32 out
    gemm_out<<<dim3(64, 8), blk, 0, stream>>>(attno, Wo_t, out);
}

// Round 22
// 94.064 us; speedup vs baseline: 1.0554x; 1.0554x over previous
//
#include <hip/hip_runtime.h>
#include <math.h>

#define AS3 __attribute__((address_space(3)))
#define AS1 __attribute__((address_space(1)))

typedef unsigned short u16;
typedef unsigned int u32;
typedef __bf16 bf16_t;
typedef bf16_t bf16x8 __attribute__((ext_vector_type(8)));
typedef float f32x4 __attribute__((ext_vector_type(4)));
typedef float f32x16 __attribute__((ext_vector_type(16)));
typedef unsigned short u16x4 __attribute__((ext_vector_type(4)));
typedef unsigned short u16x8 __attribute__((ext_vector_type(8)));
typedef unsigned int u32x4 __attribute__((ext_vector_type(4)));

#define NH 16
#define DK 64
#define DC 256
#define DM 1024
#define BB 2
#define SS 2048
#define TT (BB*SS)

__device__ __forceinline__ u16 f2bf(float f) {
    unsigned u = __builtin_bit_cast(unsigned, f);
    unsigned r = (u + 0x7FFFu + ((u >> 16) & 1u)) >> 16;
    return (u16)r;
}

__device__ __forceinline__ float bf2f(u16 h) {
    u32 u = ((u32)h) << 16;
    return __builtin_bit_cast(float, u);
}

__device__ __forceinline__ u32 cvtpk_bf16(float a, float b) {
    u32 d;
    asm("v_cvt_pk_bf16_f32 %0, %1, %2" : "=v"(d) : "v"(a), "v"(b));
    return d;
}

__device__ __forceinline__ bf16x8 lds_frag(const char* p) {
    return __builtin_bit_cast(bf16x8, *reinterpret_cast<const u16x8*>(p));
}

// ---------------- prep: 6 weight transposes (fp32 [K][N] -> bf16 [N][K]) ----------------
__global__ __launch_bounds__(256) void prep(const float* w0, const float* w1, const float* w2,
                                            const float* w3, const float* w4, const float* w5,
                                            u16* d0, u16* d1, u16* d2, u16* d3, u16* d4, u16* d5) {
    __shared__ float t[32][33];
    const int z = blockIdx.z;
    const float* src; u16* dst; int R, C, opitch;
    switch (z) {
        case 0:  src = w0; dst = d0; R = 1024; C = 256;  opitch = 1024; break;
        case 1:  src = w1; dst = d1; R = 1024; C = 256;  opitch = 1024; break;
        case 2:  src = w2; dst = d2; R = 256;  C = 1024; opitch = 256;  break;
        case 3:  src = w3; dst = d3; R = 256;  C = 1024; opitch = 256;  break;
        case 4:  src = w4; dst = d4; R = 256;  C = 1024; opitch = 256;  break;
        default: src = w5; dst = d5; R = 1024; C = 1024; opitch = 1024; break;
    }
    int c0 = blockIdx.x * 32, r0 = blockIdx.y * 32;
    if (c0 >= C || r0 >= R) return;
    int tx = threadIdx.x & 31, ty = threadIdx.x >> 5;
    #pragma unroll
    for (int p = 0; p < 4; ++p)
        t[ty + 8 * p][tx] = src[(r0 + ty + 8 * p) * C + c0 + tx];
    __syncthreads();
    #pragma unroll
    for (int p = 0; p < 4; ++p)
        dst[(c0 + ty + 8 * p) * opitch + r0 + tx] = f2bf(t[tx][ty + 8 * p]);
}

// ---------------- gemm_dqkv: c_qkv[4096,512] = x(f32) @ Wdqkv_t^T, BK=64 ----------------
// grid (64, 8): blockIdx.x = bm-panel -> all 8 bn-tiles share the A-panel on one XCD L2
__global__ __launch_bounds__(256) void gemm_dqkv(const float* __restrict__ X,
                                                 const u16* __restrict__ Bt,
                                                 u16* __restrict__ Cc) {
    __shared__ u16 As[2][64 * 32];
    __shared__ u16 Bs[2][64 * 32];
    const int tid = threadIdx.x;
    const int lane = tid & 63;
    const int w = tid >> 6;
    const int wr = w >> 1, wc = w & 1;
    const int bm = blockIdx.x * 64, bn = blockIdx.y * 64;
    const int l15 = lane & 15, l4 = lane >> 4;
    const int arow = tid >> 2, akc = (tid & 3) * 8;

    f32x4 acc[2][2] = {};

    for (int k0 = 0; k0 < 1024; k0 += 64) {
        #pragma unroll
        for (int h = 0; h < 2; ++h) {
            const float* xp = X + (size_t)(bm + arow) * 1024 + k0 + h * 32 + akc;
            float4 v0 = *reinterpret_cast<const float4*>(xp);
            float4 v1 = *reinterpret_cast<const float4*>(xp + 4);
            u32x4 o;
            o.x = cvtpk_bf16(v0.x, v0.y);
            o.y = cvtpk_bf16(v0.z, v0.w);
            o.z = cvtpk_bf16(v1.x, v1.y);
            o.w = cvtpk_bf16(v1.z, v1.w);
            *reinterpret_cast<u32x4*>(&As[h][arow * 32 + akc]) = o;
        }
        #pragma unroll
        for (int h = 0; h < 2; ++h) {
            __builtin_amdgcn_global_load_lds(
                (const AS1 void*)(Bt + (size_t)(bn + arow) * 1024 + k0 + h * 32 + akc),
                (AS3 void*)((AS3 char*)(AS3 void*)&Bs[h][0] + w * 1024), 16, 0, 0);
        }
        __syncthreads();
        #pragma unroll
        for (int h = 0; h < 2; ++h) {
            bf16x8 a[2], b[2];
            #pragma unroll
            for (int m = 0; m < 2; ++m)
                a[m] = __builtin_bit_cast(bf16x8,
                    *reinterpret_cast<const u16x8*>(&As[h][(wr * 32 + m * 16 + l15) * 32 + l4 * 8]));
            #pragma unroll
            for (int n = 0; n < 2; ++n)
                b[n] = __builtin_bit_cast(bf16x8,
                    *reinterpret_cast<const u16x8*>(&Bs[h][(wc * 32 + n * 16 + l15) * 32 + l4 * 8]));
            #pragma unroll
            for (int m = 0; m < 2; ++m)
                #pragma unroll
                for (int n = 0; n < 2; ++n)
                    acc[m][n] = __builtin_amdgcn_mfma_f32_16x16x32_bf16(a[m], b[n], acc[m][n], 0, 0, 0);
        }
        __syncthreads();
    }
    #pragma unroll
    for (int m = 0; m < 2; ++m) {
        int row = bm + wr * 32 + m * 16 + l4 * 4;
        #pragma unroll
        for (int j = 0; j < 4; ++j)
            #pragma unroll
            for (int n = 0; n < 2; ++n) {
                int col = bn + wc * 32 + n * 16 + l15;
                Cc[(size_t)(row + j) * 512 + col] = f2bf(acc[m][n][j]);
            }
    }
}

// ---------------- gemm_out: out[4096,1024](f32) = attno @ Wo_t^T, BK=64 ----------------
// grid (64, 8): blockIdx.x = bm-panel (same-XCD A-panel sharing)
__global__ __launch_bounds__(256) void gemm_out(const u16* __restrict__ A,
                                                const u16* __restrict__ Bt,
                                                float* __restrict__ C) {
    __shared__ u16 As[2][64 * 32];
    __shared__ u16 Bs[2][128 * 32];
    const int tid = threadIdx.x;
    const int lane = tid & 63;
    const int w = tid >> 6;
    const int wr = w >> 1, wc = w & 1;
    const int bm = blockIdx.x * 64, bn = blockIdx.y * 128;
    const int l15 = lane & 15, l4 = lane >> 4;

    f32x4 acc[2][4] = {};

    for (int k0 = 0; k0 < 1024; k0 += 64) {
        #pragma unroll
        for (int h = 0; h < 2; ++h) {
            {
                int db = tid * 16;
                int row = db >> 6;
                int kc = (db & 63) >> 1;
                __builtin_amdgcn_global_load_lds(
                    (const AS1 void*)(A + (size_t)(bm + row) * 1024 + k0 + h * 32 + kc),
                    (AS3 void*)((AS3 char*)(AS3 void*)&As[h][0] + w * 1024), 16, 0, 0);
            }
            #pragma unroll
            for (int i = 0; i < 2; ++i) {
                int db = i * 4096 + tid * 16;
                int row = db >> 6;
                int kc = (db & 63) >> 1;
                __builtin_amdgcn_global_load_lds(
                    (const AS1 void*)(Bt + (size_t)(bn + row) * 1024 + k0 + h * 32 + kc),
                    (AS3 void*)((AS3 char*)(AS3 void*)&Bs[h][0] + i * 4096 + w * 1024), 16, 0, 0);
            }
        }
        __syncthreads();
        #pragma unroll
        for (int h = 0; h < 2; ++h) {
            bf16x8 a[2], b[4];
            #pragma unroll
            for (int m = 0; m < 2; ++m)
                a[m] = __builtin_bit_cast(bf16x8,
                    *reinterpret_cast<const u16x8*>(&As[h][(wr * 32 + m * 16 + l15) * 32 + l4 * 8]));
            #pragma unroll
            for (int n = 0; n < 4; ++n)
                b[n] = __builtin_bit_cast(bf16x8,
                    *reinterpret_cast<const u16x8*>(&Bs[h][(wc * 64 + n * 16 + l15) * 32 + l4 * 8]));
            #pragma unroll
            for (int m = 0; m < 2; ++m)
                #pragma unroll
                for (int n = 0; n < 4; ++n)
                    acc[m][n] = __builtin_amdgcn_mfma_f32_16x16x32_bf16(a[m], b[n], acc[m][n], 0, 0, 0);
        }
        __syncthreads();
    }
    #pragma unroll
    for (int m = 0; m < 2; ++m) {
        int row = bm + wr * 32 + m * 16 + l4 * 4;
        #pragma unroll
        for (int j = 0; j < 4; ++j)
            #pragma unroll
            for (int n = 0; n < 4; ++n) {
                int col = bn + wc * 64 + n * 16 + l15;
                C[(size_t)(row + j) * 1024 + col] = acc[m][n][j];
            }
    }
}

// ---------------- MFMA GEMM body (128x128, BK=32) for the fused QKV projection ----------------
template <int OUT_MODE>
__device__ __forceinline__ void gemm_body128(const u16* __restrict__ A, int lda,
                                             const u16* __restrict__ Bt, int ldb,
                                             void* __restrict__ C, int ldc, int K,
                                             int bm, int bn, u16* As, u16* Bs) {
    const int tid = threadIdx.x;
    const int lane = tid & 63;
    const int w = tid >> 6;
    const int wr = w >> 1, wc = w & 1;
    const int l15 = lane & 15, l4 = lane >> 4;

    f32x4 acc[4][4] = {};

    for (int k0 = 0; k0 < K; k0 += 32) {
        #pragma unroll
        for (int i = 0; i < 2; ++i) {
            int db = i * 4096 + tid * 16;
            int row = db >> 6;
            int kc = (db & 63) >> 1;
            __builtin_amdgcn_global_load_lds(
                (const AS1 void*)(A + (size_t)(bm + row) * lda + k0 + kc),
                (AS3 void*)((AS3 char*)(AS3 void*)As + i * 4096 + w * 1024), 16, 0, 0);
            __builtin_amdgcn_global_load_lds(
                (const AS1 void*)(Bt + (size_t)(bn + row) * ldb + k0 + kc),
                (AS3 void*)((AS3 char*)(AS3 void*)Bs + i * 4096 + w * 1024), 16, 0, 0);
        }
        __syncthreads();
        bf16x8 a[4], b[4];
        #pragma unroll
        for (int m = 0; m < 4; ++m)
            a[m] = __builtin_bit_cast(bf16x8,
                *reinterpret_cast<const u16x8*>(&As[(wr * 64 + m * 16 + l15) * 32 + l4 * 8]));
        #pragma unroll
        for (int n = 0; n < 4; ++n)
            b[n] = __builtin_bit_cast(bf16x8,
                *reinterpret_cast<const u16x8*>(&Bs[(wc * 64 + n * 16 + l15) * 32 + l4 * 8]));
        #pragma unroll
        for (int m = 0; m < 4; ++m)
            #pragma unroll
            for (int n = 0; n < 4; ++n)
                acc[m][n] = __builtin_amdgcn_mfma_f32_16x16x32_bf16(a[m], b[n], acc[m][n], 0, 0, 0);
        __syncthreads();
    }
    if (OUT_MODE == 2) {
        #pragma unroll
        for (int m = 0; m < 4; ++m) {
            int row = bm + wr * 64 + m * 16 + l4 * 4;   // = b*2048 + s, s%4==0
            int vrow_base = (row >> 11) << 10;
            int scol = row & 2047;
            #pragma unroll
            for (int n = 0; n < 4; ++n) {
                int col = bn + wc * 64 + n * 16 + l15;   // v-dim
                u16x4 ov;
                ov[0] = f2bf(acc[m][n][0]); ov[1] = f2bf(acc[m][n][1]);
                ov[2] = f2bf(acc[m][n][2]); ov[3] = f2bf(acc[m][n][3]);
                *reinterpret_cast<u16x4*>((u16*)C + (size_t)(vrow_base + col) * 2048 + scol) = ov;
            }
        }
    } else {
        #pragma unroll
        for (int m = 0; m < 4; ++m) {
            int row = bm + wr * 64 + m * 16 + l4 * 4;
            #pragma unroll
            for (int j = 0; j < 4; ++j)
                #pragma unroll
                for (int n = 0; n < 4; ++n) {
                    int col = bn + wc * 64 + n * 16 + l15;
                    ((u16*)C)[(size_t)(row + j) * ldc + col] = f2bf(acc[m][n][j]);
                }
        }
    }
}

// fused Q + K + V up-projection, K=256. grid (32, 24): blockIdx.x = bm-panel.
__global__ __launch_bounds__(256) void gemm_qkv(const u16* __restrict__ c_qkv,
                                                const u16* __restrict__ Wuq_t,
                                                const u16* __restrict__ Wukv_t,
                                                u16* __restrict__ Qb, u16* __restrict__ Kb,
                                                u16* __restrict__ Vt) {
    __shared__ u16 As[128 * 32];
    __shared__ u16 Bs[128 * 32];
    const int by = blockIdx.y;
    const int bm = blockIdx.x * 128;
    if (by < 8) {
        gemm_body128<1>(c_qkv, 512, Wuq_t, 256, Qb, 1024, 256,
                        bm, by * 128, As, Bs);
    } else if (by < 16) {
        gemm_body128<1>(c_qkv + 256, 512, Wukv_t, 256, Kb, 1024, 256,
                        bm, (by - 8) * 128, As, Bs);
    } else {
        gemm_body128<2>(c_qkv + 256, 512, Wukv_t + 1024 * 256, 256, Vt, 0, 256,
                        bm, (by - 16) * 128, As, Bs);
    }
}

// ---------------- MFMA causal flash attention v13 (R19/R20-verified) ----------------
__global__ __launch_bounds__(256, 4) void attn_mfma6(const u16* __restrict__ Qb,
                                                     const u16* __restrict__ Kb,
                                                     const u16* __restrict__ VtG,
                                                     u16* __restrict__ O) {
    __shared__ char lds[32768];   // 2 slots x (8KB K + 8KB V); combine aliases 19.5 KB
    const int bid = blockIdx.x;
    const int g = bid >> 8, u = (bid >> 5) & 7;
    const int bq = (g == 0) ? (31 - u) : (g == 1) ? (16 + u) : (g == 2) ? (15 - u) : u;
    const int bh = bid & 31;
    const int b = bh >> 4, head = bh & 15;
    const int tid = threadIdx.x;
    const int w = tid >> 6;
    const int lane = tid & 63;
    const int l31 = lane & 31, hi = lane >> 5;
    const int r7 = l31 & 7;
    const int pair = w >> 1, sub = w & 1;
    const int q0 = bq * 64;
    const int qg = q0 + sub * 32 + l31;
    const int rounds = (bq >> 1) + 1;
    const float c2 = 0.125f * 1.44269504088896340736f;  // scale * log2(e)

    // Q fragments (B-operand): Q[q][16kc + 8hi + 0..7]
    bf16x8 qf[4];
    {
        const u16* qp = Qb + (size_t)(b * SS + qg) * 1024 + head * 64 + hi * 8;
        #pragma unroll
        for (int kc = 0; kc < 4; ++kc)
            qf[kc] = __builtin_bit_cast(bf16x8, *reinterpret_cast<const u16x8*>(qp + kc * 16));
    }

    f32x16 acc0 = {}, acc1 = {};   // O^T partial: d rows (0..31 / 32..63), col = q
    float lrow = 0.f;

#define STAGE2(r_) do { \
    _Pragma("unroll") \
    for (int p_ = 0; p_ < 2; ++p_) { \
        int kt_ = 2 * (r_) + p_; \
        if (kt_ <= bq) { \
            int k0_ = kt_ * 64; \
            char* base_ = lds + p_ * 16384; \
            _Pragma("unroll") \
            for (int c_ = 0; c_ < 2; ++c_) { \
                int i_ = tid + 256 * c_; int row_ = i_ >> 3; int sc_ = (i_ & 7) ^ (row_ & 7); \
                __builtin_amdgcn_global_load_lds( \
                    (const AS1 void*)(Kb + (size_t)(b * SS + k0_ + row_) * 1024 + head * 64 + sc_ * 8), \
                    (AS3 void*)((AS3 char*)(AS3 void*)base_ + c_ * 4096 + w * 1024), 16, 0, 0); \
                __builtin_amdgcn_global_load_lds( \
                    (const AS1 void*)(VtG + (size_t)(bh * 64 + row_) * 2048 + k0_ + sc_ * 8), \
                    (AS3 void*)((AS3 char*)(AS3 void*)base_ + 8192 + c_ * 4096 + w * 1024), 16, 0, 0); \
            } \
        } \
    } } while (0)

    for (int r = 0; r < rounds; ++r) {
        STAGE2(r);
        __syncthreads();   // staging complete (implies vmcnt drain)
        const int kt = 2 * r + pair;
        if (kt <= bq) {
            const char* Kb_ = lds + pair * 16384;
            const char* Vb_ = Kb_ + 8192;
            const int k0 = kt * 64;
            // S^T = K @ Q^T
            f32x16 s0 = {}, s1 = {};
            __builtin_amdgcn_s_setprio(1);
            #pragma unroll
            for (int kc = 0; kc < 4; ++kc) {
                bf16x8 kf0 = lds_frag(Kb_ + (l31) * 128 + ((2 * kc + hi) ^ r7) * 16);
                bf16x8 kf1 = lds_frag(Kb_ + (32 + l31) * 128 + ((2 * kc + hi) ^ r7) * 16);
                s0 = __builtin_amdgcn_mfma_f32_32x32x16_bf16(kf0, qf[kc], s0, 0, 0, 0);
                s1 = __builtin_amdgcn_mfma_f32_32x32x16_bf16(kf1, qf[kc], s1, 0, 0, 0);
            }
            __builtin_amdgcn_s_setprio(0);
            if (kt == bq) {   // diagonal tile: causal mask (exp2 underflows to 0)
                const int lim = qg - k0 - hi * 4;
                #pragma unroll
                for (int r2 = 0; r2 < 16; ++r2) {
                    const int ko = (r2 & 3) + 8 * (r2 >> 2);
                    s0[r2] = (ko > lim) ? -3.0e38f : s0[r2];
                    s1[r2] = (ko + 32 > lim) ? -3.0e38f : s1[r2];
                }
            }
            // max-free softmax: p = exp2(s * c2)
            #pragma unroll
            for (int r2 = 0; r2 < 16; ++r2) {
                s0[r2] = exp2f(s0[r2] * c2);
                s1[r2] = exp2f(s1[r2] * c2);
            }
            float c8[8];
            #pragma unroll
            for (int i = 0; i < 8; ++i)
                c8[i] = (s0[2 * i] + s0[2 * i + 1]) + (s1[2 * i] + s1[2 * i + 1]);
            float rsum = ((c8[0] + c8[1]) + (c8[2] + c8[3])) + ((c8[4] + c8[5]) + (c8[6] + c8[7]));
            rsum += __shfl_xor(rsum, 32);
            lrow += rsum;
            // pack P to bf16 pairs
            u32 cg0[4][2], cg1[4][2];
            #pragma unroll
            for (int gg = 0; gg < 4; ++gg) {
                #pragma unroll
                for (int w2 = 0; w2 < 2; ++w2) {
                    cg0[gg][w2] = cvtpk_bf16(s0[4 * gg + 2 * w2], s0[4 * gg + 2 * w2 + 1]);
                    cg1[gg][w2] = cvtpk_bf16(s1[4 * gg + 2 * w2], s1[4 * gg + 2 * w2 + 1]);
                }
            }
            // assemble P frags via shfl_xor(32): pa[ks] = P[q][16ks + 8hi + 0..7]
            bf16x8 pa[4];
            #pragma unroll
            for (int ks = 0; ks < 4; ++ks) {
                const int g0 = (2 * ks) & 3, g1 = g0 + 1;
                u32 a0, a1, b0, b1;
                if (ks < 2) { a0 = cg0[g0][0]; a1 = cg0[g0][1]; b0 = cg0[g1][0]; b1 = cg0[g1][1]; }
                else        { a0 = cg1[g0][0]; a1 = cg1[g0][1]; b0 = cg1[g1][0]; b1 = cg1[g1][1]; }
                u32 pa0 = (u32)__shfl_xor((int)a0, 32);
                u32 pa1 = (u32)__shfl_xor((int)a1, 32);
                u32 pb0 = (u32)__shfl_xor((int)b0, 32);
                u32 pb1 = (u32)__shfl_xor((int)b1, 32);
                u32x4 f;
                f.x = hi ? pb0 : a0;
                f.y = hi ? pb1 : a1;
                f.z = hi ? b0 : pa0;
                f.w = hi ? b1 : pa1;
                pa[ks] = __builtin_bit_cast(bf16x8, f);
            }
            // O^T += V^T @ P^T
            __builtin_amdgcn_s_setprio(1);
            #pragma unroll
            for (int ks = 0; ks < 4; ++ks) {
                bf16x8 vf0 = lds_frag(Vb_ + (l31) * 128 + ((2 * ks + hi) ^ r7) * 16);
                bf16x8 vf1 = lds_frag(Vb_ + (32 + l31) * 128 + ((2 * ks + hi) ^ r7) * 16);
                acc0 = __builtin_amdgcn_mfma_f32_32x32x16_bf16(vf0, pa[ks], acc0, 0, 0, 0);
                acc1 = __builtin_amdgcn_mfma_f32_32x32x16_bf16(vf1, pa[ks], acc1, 0, 0, 0);
            }
            __builtin_amdgcn_s_setprio(0);
        }
        __syncthreads();   // all reads done; safe to restage next round
    }
#undef STAGE2

    // write partials to LDS as bf16 (aliases staging region; all compute done)
    u16* partb = (u16*)lds;                      // [4][32][72] u16 = 18432 B
    float* mls = (float*)(lds + 18432);          // [4][32]     = 512 B (l only)
    #pragma unroll
    for (int r2 = 0; r2 < 16; r2 += 2) {
        const int d0 = (r2 & 3) + 8 * (r2 >> 2) + 4 * hi;
        *reinterpret_cast<u32*>(&partb[(w * 32 + l31) * 72 + d0]) =
            cvtpk_bf16(acc0[r2], acc0[r2 + 1]);
        *reinterpret_cast<u32*>(&partb[(w * 32 + l31) * 72 + d0 + 32]) =
            cvtpk_bf16(acc1[r2], acc1[r2 + 1]);
    }
    if (hi == 0 && lane < 32) mls[w * 32 + l31] = lrow;
    __syncthreads();

    // combine 2 partials (plain sums): thread -> q = tid>>2 (0..63), d-seg = (tid&3)*16
    {
        const int q = tid >> 2, ds0 = (tid & 3) * 16;
        const int s_ = q >> 5, qq = q & 31;
        const int wa_ = s_, wb_ = 2 + s_;
        float lt = mls[wa_ * 32 + qq] + mls[wb_ * 32 + qq];
        float inv = 1.0f / lt;
        u16x8 pa0 = *reinterpret_cast<const u16x8*>(&partb[(wa_ * 32 + qq) * 72 + ds0]);
        u16x8 pa1 = *reinterpret_cast<const u16x8*>(&partb[(wa_ * 32 + qq) * 72 + ds0 + 8]);
        u16x8 pb0 = *reinterpret_cast<const u16x8*>(&partb[(wb_ * 32 + qq) * 72 + ds0]);
        u16x8 pb1 = *reinterpret_cast<const u16x8*>(&partb[(wb_ * 32 + qq) * 72 + ds0 + 8]);
        u16x8 ov0, ov1;
        #pragma unroll
        for (int i = 0; i < 8; ++i) {
            float v0 = bf2f(pa0[i]) + bf2f(pb0[i]);
            float v1 = bf2f(pa1[i]) + bf2f(pb1[i]);
            ov0[i] = f2bf(v0 * inv);
            ov1[i] = f2bf(v1 * inv);
        }
        u16* op = O + (size_t)(b * SS + q0 + q) * 1024 + head * 64 + ds0;
        *reinterpret_cast<u16x8*>(op) = ov0;
        *reinterpret_cast<u16x8*>(op + 8) = ov1;
    }
}

// ---------------- launch ----------------

extern "C" void kernel_launch(void* const* d_in, const int* in_sizes, int n_in,
                              void* d_out, int out_size, void* d_ws, size_t ws_size,
                              hipStream_t stream) {
    const float* x     = (const float*)d_in[0];
    const float* W_dq  = (const float*)d_in[1];
    const float* W_uq  = (const float*)d_in[2];
    const float* W_dkv = (const float*)d_in[3];
    const float* W_uk  = (const float*)d_in[4];
    const float* W_uv  = (const float*)d_in[5];
    const float* W_o   = (const float*)d_in[6];
    float* out = (float*)d_out;

    char* ws = (char*)d_ws;
    u16* c_qkv   = (u16*)(ws + (8u << 20));             // 4 MB   [4096][512]
    u16* Qb      = (u16*)(ws + (12u << 20));            // 8 MB   [4096][1024]
    u16* Kb      = (u16*)(ws + (20u << 20));            // 8 MB   [4096][1024] (K only)
    u16* Vt      = (u16*)(ws + (36u << 20));            // 8 MB   [2048][2048]
    u16* attno   = (u16*)(ws + (44u << 20));            // 8 MB   [4096][1024]
    u16* Wdqkv_t = (u16*)(ws + (52u << 20));            // 1 MB   [512][1024]
    u16* Wuq_t   = (u16*)(ws + (53u << 20));            // 0.5 MB [1024][256]
    u16* Wukv_t  = (u16*)(ws + (53u << 20) + (512u << 10)); // 1 MB [2048][256]
    u16* Wo_t    = (u16*)(ws + (55u << 20));            // 2 MB   [1024][1024]

    dim3 blk(256);
    // 6 weight transposes
    prep<<<dim3(32, 32, 6), blk, 0, stream>>>(W_dq, W_dkv, W_uq, W_uk, W_uv, W_o,
        Wdqkv_t, Wdqkv_t + 256 * 1024, Wuq_t, Wukv_t, Wukv_t + 1024 * 256, Wo_t);
    // c_qkv = x(f32) @ [W_dq | W_dkv]   grid (64,8): A-panel-per-XCD
    gemm_dqkv<<<dim3(64, 8), blk, 0, stream>>>(x, Wdqkv_t, c_qkv);
    // Q | K | V(transposed) up-projection, K=256, grid (32,24): A-panel-per-XCD
    gemm_qkv<<<dim3(32, 24), blk, 0, stream>>>(c_qkv, Wuq_t, Wukv_t, Qb, Kb, Vt);
    // attention: 1024 blocks, balanced per-CU bq mapping, max-free softmax
    attn_mfma6<<<dim3(1024), blk, 0, stream>>>(Qb, Kb, Vt, attno);
    // out = attno @ W_o   grid (64,8): A-panel-per-XCD, fp32 out
    gemm_out<<<dim3(64, 8), blk, 0, stream>>>(attno, Wo_t, out);
}